// Round 1
// baseline (744.210 us; speedup 1.0000x reference)
//
#include <hip/hip_runtime.h>

#define NNODES 100000
#define FDIM 128
#define NLAYERS 5

typedef __bf16 bf16_t;
typedef bf16_t bf16x8 __attribute__((ext_vector_type(8)));
typedef float  f32x4  __attribute__((ext_vector_type(4)));

__device__ __forceinline__ bf16_t f2bf(float f){ return (bf16_t)f; }

// ---------------- CSR build ----------------
__global__ void deg_kernel(const int* __restrict__ dstv, int* __restrict__ deg, int E){
  int e = blockIdx.x*256 + threadIdx.x;
  if(e < E) atomicAdd(&deg[dstv[e]], 1);
}

// per-chunk (1024 elems) exclusive scan, 256 threads x 4 elems
__global__ void scan1_kernel(const int* __restrict__ deg, int* __restrict__ row_start,
                             int* __restrict__ sums, int n){
  __shared__ int sm[256];
  int t = threadIdx.x;
  int base = blockIdx.x*1024 + t*4;
  int v0=0,v1=0,v2=0,v3=0;
  if(base+3 < n){ int4 q = *(const int4*)(deg+base); v0=q.x; v1=q.y; v2=q.z; v3=q.w; }
  else {
    if(base   < n) v0 = deg[base];
    if(base+1 < n) v1 = deg[base+1];
    if(base+2 < n) v2 = deg[base+2];
    if(base+3 < n) v3 = deg[base+3];
  }
  int s = v0+v1+v2+v3;
  sm[t] = s;
  __syncthreads();
  for(int off=1; off<256; off<<=1){
    int y = (t>=off) ? sm[t-off] : 0;
    __syncthreads();
    sm[t] += y;
    __syncthreads();
  }
  int excl = sm[t] - s;
  if(base   < n) row_start[base]   = excl;
  if(base+1 < n) row_start[base+1] = excl+v0;
  if(base+2 < n) row_start[base+2] = excl+v0+v1;
  if(base+3 < n) row_start[base+3] = excl+v0+v1+v2;
  if(t == 255) sums[blockIdx.x] = sm[255];
}

__global__ void scan2_kernel(int* sums, int nc){
  __shared__ int sm[128];
  int t = threadIdx.x;
  int v = (t<nc) ? sums[t] : 0;
  sm[t] = v;
  __syncthreads();
  for(int off=1; off<128; off<<=1){
    int y = (t>=off) ? sm[t-off] : 0;
    __syncthreads();
    sm[t] += y;
    __syncthreads();
  }
  if(t<nc) sums[t] = sm[t] - v;   // exclusive chunk offsets
}

__global__ void scan3_kernel(int* row_start, const int* __restrict__ sums, int n, int E){
  int i = blockIdx.x*256 + threadIdx.x;
  if(i < n)       row_start[i] += sums[i>>10];
  else if(i == n) row_start[n]  = E;
}

__global__ void fill_kernel(const int* __restrict__ srcv, const int* __restrict__ dstv,
                            const int* __restrict__ row_start, int* __restrict__ cnt,
                            int* __restrict__ csr, int E){
  int e = blockIdx.x*256 + threadIdx.x;
  if(e < E){
    int d = dstv[e];
    int p = atomicAdd(&cnt[d], 1);
    csr[row_start[d] + p] = srcv[e];
  }
}

// ---------------- per-node gather (agg = segment_sum(x[src], dst)) ----------------
__global__ __launch_bounds__(256) void gather_kernel(const float* __restrict__ x,
                                                     const int* __restrict__ row_start,
                                                     const int* __restrict__ csr,
                                                     float* __restrict__ agg, int n){
  int wid  = (blockIdx.x*256 + threadIdx.x) >> 6;   // one wave per node
  int lane = threadIdx.x & 63;
  if(wid >= n) return;
  int s0 = row_start[wid];
  int s1 = row_start[wid+1];
  float ax = 0.f, ay = 0.f;
  for(int i = s0; i < s1; ++i){
    int s = csr[i];
    const float2 v = *(const float2*)(x + (long)s*FDIM + lane*2);
    ax += v.x; ay += v.y;
  }
  float2 o; o.x = ax; o.y = ay;
  *(float2*)(agg + (long)wid*FDIM + lane*2) = o;
}

// ---------------- weight prepack: Wc=[Wr;Wroot] -> bf16 MFMA B-fragments ----------------
// frag idx = (l*64 + kk*8+cb)*64 + lane ; 8 bf16 per frag
// B layout (16x16x32): col = lane&15, k = kk*32 + (lane>>4)*8 + e
__global__ void wprep_kernel(const float* __restrict__ Wrel, const float* __restrict__ Wroot,
                             bf16_t* __restrict__ Bp){
  int gid = blockIdx.x*256 + threadIdx.x;
  if(gid >= NLAYERS*64*64) return;
  int lane = gid & 63;
  int fg   = (gid>>6) & 63;
  int l    = gid >> 12;
  int kk = fg >> 3, cb = fg & 7;
  int kbase = kk*32 + (lane>>4)*8;
  int col   = cb*16 + (lane&15);
  bf16_t tmp[8];
  #pragma unroll
  for(int e=0;e<8;e++){
    int k = kbase + e;
    float v = (k < FDIM) ? Wrel [l*FDIM*FDIM + k*FDIM + col]
                         : Wroot[l*FDIM*FDIM + (k-FDIM)*FDIM + col];
    tmp[e] = f2bf(v);
  }
  bf16_t* o = Bp + (long)gid*8;
  #pragma unroll
  for(int e=0;e<8;e++) o[e] = tmp[e];
}

// ---------------- fused GEMM: out = epi(agg@Wr + x@Wroot + b) ----------------
// wave owns 16 rows x 128 cols; A read direct from global fp32, cvt to bf16 in-reg.
__global__ __launch_bounds__(256) void gemm_kernel(
    const float* __restrict__ Aagg, const float* __restrict__ Ain,
    const bf16_t* __restrict__ Bp, const float* __restrict__ bias,
    float* __restrict__ out, int relu, int resf, int ntiles, int nwaves){
  int lane = threadIdx.x & 63;
  int gw   = (blockIdx.x*256 + threadIdx.x) >> 6;
  int r_lo = lane & 15;     // A row within 16-tile / output col within 16-block
  int kgrp = lane >> 4;     // 0..3
  float breg[8];
  #pragma unroll
  for(int cb=0;cb<8;cb++) breg[cb] = bias[cb*16 + r_lo];

  for(int t = gw; t < ntiles; t += nwaves){
    long r0 = (long)t*16;
    f32x4 acc[8] = {};
    const float* pa = Aagg + (r0 + r_lo)*FDIM + kgrp*8;
    const float* pi = Ain  + (r0 + r_lo)*FDIM + kgrp*8;
    #pragma unroll
    for(int kk=0;kk<8;kk++){
      const float* ap = (kk<4) ? (pa + kk*32) : (pi + (kk-4)*32);
      float4 q0 = *(const float4*)ap;
      float4 q1 = *(const float4*)(ap+4);
      bf16x8 a;
      a[0]=f2bf(q0.x); a[1]=f2bf(q0.y); a[2]=f2bf(q0.z); a[3]=f2bf(q0.w);
      a[4]=f2bf(q1.x); a[5]=f2bf(q1.y); a[6]=f2bf(q1.z); a[7]=f2bf(q1.w);
      #pragma unroll
      for(int cb=0;cb<8;cb++){
        bf16x8 b = *(const bf16x8*)(Bp + (((kk<<3)|cb)*64 + lane)*8);
        acc[cb] = __builtin_amdgcn_mfma_f32_16x16x32_bf16(a, b, acc[cb], 0, 0, 0);
      }
    }
    // epilogue: C/D layout col=lane&15, row=(lane>>4)*4+reg  [m89]
    #pragma unroll
    for(int cb=0;cb<8;cb++){
      int col = cb*16 + r_lo;
      #pragma unroll
      for(int r=0;r<4;r++){
        long row = r0 + kgrp*4 + r;
        float v = acc[cb][r] + breg[cb];
        if(relu) v = fmaxf(v, 0.f);
        if(resf) v += Ain[row*FDIM + col];
        out[row*FDIM + col] = v;
      }
    }
  }
}

extern "C" void kernel_launch(void* const* d_in, const int* in_sizes, int n_in,
                              void* d_out, int out_size, void* d_ws, size_t ws_size,
                              hipStream_t stream){
  const float* x     = (const float*)d_in[0];
  const int*   ei    = (const int*)  d_in[1];
  const float* Wrel  = (const float*)d_in[2];
  const float* brel  = (const float*)d_in[3];
  const float* Wroot = (const float*)d_in[4];
  float* out = (float*)d_out;

  const int N = NNODES;
  const int E = in_sizes[1] / 2;
  const int* srcv = ei;
  const int* dstv = ei + E;

  char* w = (char*)d_ws;
  auto alloc = [&](size_t b)->char*{ char* p = w; w += (b + 255) & ~(size_t)255; return p; };
  float*  h_a       = (float*) alloc((size_t)N*FDIM*4);
  float*  h_b       = (float*) alloc((size_t)N*FDIM*4);
  int*    deg       = (int*)   alloc((size_t)N*4);
  int*    cnt       = (int*)   alloc((size_t)N*4);
  int*    row_start = (int*)   alloc((size_t)(N+1)*4);
  int*    csr       = (int*)   alloc((size_t)E*4);
  bf16_t* Bp        = (bf16_t*)alloc((size_t)NLAYERS*4096*8*2);
  int*    sums      = (int*)   alloc(512);

  hipMemsetAsync(deg, 0, (size_t)N*4, stream);
  hipMemsetAsync(cnt, 0, (size_t)N*4, stream);

  int eb = (E + 255) / 256;
  int nchunks = (N + 1023) / 1024;
  deg_kernel <<<eb, 256, 0, stream>>>(dstv, deg, E);
  scan1_kernel<<<nchunks, 256, 0, stream>>>(deg, row_start, sums, N);
  scan2_kernel<<<1, 128, 0, stream>>>(sums, nchunks);
  scan3_kernel<<<(N + 1 + 255)/256, 256, 0, stream>>>(row_start, sums, N, E);
  fill_kernel<<<eb, 256, 0, stream>>>(srcv, dstv, row_start, cnt, csr, E);
  wprep_kernel<<<(NLAYERS*4096 + 255)/256, 256, 0, stream>>>(Wrel, Wroot, Bp);

  const int ntiles  = N / 16;       // 6250, exact
  const int gblocks = 782;          // ~2 tiles per wave
  const int nwaves  = gblocks * 4;

  struct Lay { const float* in; float* agg; float* o; int relu; int res; };
  Lay L[5] = {
    { x,   out, h_a, 1, 0 },   // h1 = relu(gc0(x))
    { h_a, out, h_b, 1, 1 },   // h2 = relu(gc1(h1)) + h1
    { h_b, out, h_a, 1, 1 },   // h3
    { h_a, out, h_b, 1, 1 },   // h4
    { h_b, h_a, out, 0, 1 },   // h5 = gc4(h4) + h4  -> d_out
  };
  for(int l=0; l<NLAYERS; l++){
    gather_kernel<<<N/4, 256, 0, stream>>>(L[l].in, row_start, csr, L[l].agg, N);
    gemm_kernel  <<<gblocks, 256, 0, stream>>>(L[l].agg, L[l].in,
                                               Bp + (size_t)l*4096*8,
                                               brel + l*FDIM,
                                               L[l].o, L[l].relu, L[l].res,
                                               ntiles, nwaves);
  }
}

// Round 2
// 601.426 us; speedup vs baseline: 1.2374x; 1.2374x over previous
//
#include <hip/hip_runtime.h>

#define NNODES 100000
#define FDIM 128
#define NLAYERS 5

typedef __bf16 bf16_t;
typedef bf16_t bf16x8 __attribute__((ext_vector_type(8)));
typedef float  f32x4  __attribute__((ext_vector_type(4)));

__device__ __forceinline__ bf16_t f2bf(float f){ return (bf16_t)f; }
__device__ __forceinline__ float bfbits_lo(unsigned u){ // low ushort -> float
  unsigned b = u << 16; return __builtin_bit_cast(float, b);
}
__device__ __forceinline__ float bfbits_hi(unsigned u){ // high ushort -> float
  unsigned b = u & 0xffff0000u; return __builtin_bit_cast(float, b);
}
__device__ __forceinline__ unsigned short bfb(float f){
  bf16_t b = (bf16_t)f; return __builtin_bit_cast(unsigned short, b);
}

// ---------------- CSR build ----------------
__global__ void deg_kernel(const int* __restrict__ dstv, int* __restrict__ deg, int E){
  int e = blockIdx.x*256 + threadIdx.x;
  if(e < E) atomicAdd(&deg[dstv[e]], 1);
}

__global__ void scan1_kernel(const int* __restrict__ deg, int* __restrict__ row_start,
                             int* __restrict__ sums, int n){
  __shared__ int sm[256];
  int t = threadIdx.x;
  int base = blockIdx.x*1024 + t*4;
  int v0=0,v1=0,v2=0,v3=0;
  if(base+3 < n){ int4 q = *(const int4*)(deg+base); v0=q.x; v1=q.y; v2=q.z; v3=q.w; }
  else {
    if(base   < n) v0 = deg[base];
    if(base+1 < n) v1 = deg[base+1];
    if(base+2 < n) v2 = deg[base+2];
    if(base+3 < n) v3 = deg[base+3];
  }
  int s = v0+v1+v2+v3;
  sm[t] = s;
  __syncthreads();
  for(int off=1; off<256; off<<=1){
    int y = (t>=off) ? sm[t-off] : 0;
    __syncthreads();
    sm[t] += y;
    __syncthreads();
  }
  int excl = sm[t] - s;
  if(base   < n) row_start[base]   = excl;
  if(base+1 < n) row_start[base+1] = excl+v0;
  if(base+2 < n) row_start[base+2] = excl+v0+v1;
  if(base+3 < n) row_start[base+3] = excl+v0+v1+v2;
  if(t == 255) sums[blockIdx.x] = sm[255];
}

__global__ void scan2_kernel(int* sums, int nc){
  __shared__ int sm[128];
  int t = threadIdx.x;
  int v = (t<nc) ? sums[t] : 0;
  sm[t] = v;
  __syncthreads();
  for(int off=1; off<128; off<<=1){
    int y = (t>=off) ? sm[t-off] : 0;
    __syncthreads();
    sm[t] += y;
    __syncthreads();
  }
  if(t<nc) sums[t] = sm[t] - v;
}

__global__ void scan3_kernel(int* row_start, const int* __restrict__ sums, int n, int E){
  int i = blockIdx.x*256 + threadIdx.x;
  if(i < n)       row_start[i] += sums[i>>10];
  else if(i == n) row_start[n]  = E;
}

__global__ void fill_kernel(const int* __restrict__ srcv, const int* __restrict__ dstv,
                            const int* __restrict__ row_start, int* __restrict__ cnt,
                            int* __restrict__ csr, int E){
  int e = blockIdx.x*256 + threadIdx.x;
  if(e < E){
    int d = dstv[e];
    int p = atomicAdd(&cnt[d], 1);
    csr[row_start[d] + p] = srcv[e];
  }
}

// ---------------- x fp32 -> bf16 pre-convert ----------------
__global__ __launch_bounds__(256) void cvt_kernel(const float* __restrict__ x,
                                                  unsigned short* __restrict__ xb){
  long i = ((long)blockIdx.x*256 + threadIdx.x)*8;
  float4 q0 = *(const float4*)(x+i);
  float4 q1 = *(const float4*)(x+i+4);
  unsigned short o[8];
  o[0]=bfb(q0.x); o[1]=bfb(q0.y); o[2]=bfb(q0.z); o[3]=bfb(q0.w);
  o[4]=bfb(q1.x); o[5]=bfb(q1.y); o[6]=bfb(q1.z); o[7]=bfb(q1.w);
  *(ulong2*)(xb+i) = *(ulong2*)o;   // 16B store
}

// ---------------- per-node gather: agg(bf16) = sum over neighbors of h(bf16) ----------------
__global__ __launch_bounds__(256) void gather_kernel(const unsigned short* __restrict__ xb,
                                                     const int* __restrict__ row_start,
                                                     const int* __restrict__ csr,
                                                     unsigned short* __restrict__ agg, int n){
  int wid  = (blockIdx.x*256 + threadIdx.x) >> 6;   // one wave per node
  int lane = threadIdx.x & 63;
  if(wid >= n) return;
  int s0 = row_start[wid];
  int s1 = row_start[wid+1];
  float ax0=0.f, ay0=0.f, ax1=0.f, ay1=0.f;
  int i = s0;
  for(; i+2 <= s1; i += 2){
    int sA = csr[i];
    int sB = csr[i+1];
    unsigned vA = *(const unsigned*)(xb + (size_t)sA*FDIM + lane*2);
    unsigned vB = *(const unsigned*)(xb + (size_t)sB*FDIM + lane*2);
    ax0 += bfbits_lo(vA); ay0 += bfbits_hi(vA);
    ax1 += bfbits_lo(vB); ay1 += bfbits_hi(vB);
  }
  if(i < s1){
    int sA = csr[i];
    unsigned vA = *(const unsigned*)(xb + (size_t)sA*FDIM + lane*2);
    ax0 += bfbits_lo(vA); ay0 += bfbits_hi(vA);
  }
  float ax = ax0+ax1, ay = ay0+ay1;
  unsigned o = (unsigned)bfb(ax) | ((unsigned)bfb(ay) << 16);
  *(unsigned*)(agg + (size_t)wid*FDIM + lane*2) = o;
}

// ---------------- weight prepack: Wc=[Wr;Wroot] -> bf16 MFMA B-fragments ----------------
__global__ void wprep_kernel(const float* __restrict__ Wrel, const float* __restrict__ Wroot,
                             bf16_t* __restrict__ Bp){
  int gid = blockIdx.x*256 + threadIdx.x;
  if(gid >= NLAYERS*64*64) return;
  int lane = gid & 63;
  int fg   = (gid>>6) & 63;
  int l    = gid >> 12;
  int kk = fg >> 3, cb = fg & 7;
  int kbase = kk*32 + (lane>>4)*8;
  int col   = cb*16 + (lane&15);
  bf16_t tmp[8];
  #pragma unroll
  for(int e=0;e<8;e++){
    int k = kbase + e;
    float v = (k < FDIM) ? Wrel [l*FDIM*FDIM + k*FDIM + col]
                         : Wroot[l*FDIM*FDIM + (k-FDIM)*FDIM + col];
    tmp[e] = f2bf(v);
  }
  bf16_t* o = Bp + (long)gid*8;
  #pragma unroll
  for(int e=0;e<8;e++) o[e] = tmp[e];
}

// ---------------- fused GEMM: out = epi(agg@Wr + x@Wroot + b) ----------------
// A operands are bf16 row-contiguous; loads are direct bf16x8, no cvt.
__global__ __launch_bounds__(256) void gemm_kernel(
    const bf16_t* __restrict__ Aagg, const bf16_t* __restrict__ Ain,
    const bf16_t* __restrict__ Bp, const float* __restrict__ bias,
    bf16_t* __restrict__ outB, float* __restrict__ outF,
    int relu, int resf, int ntiles, int nwaves){
  int lane = threadIdx.x & 63;
  int gw   = (blockIdx.x*256 + threadIdx.x) >> 6;
  int r_lo = lane & 15;     // A row within 16-tile / output col within 16-block
  int kgrp = lane >> 4;     // 0..3
  float breg[8];
  #pragma unroll
  for(int cb=0;cb<8;cb++) breg[cb] = bias[cb*16 + r_lo];

  for(int t = gw; t < ntiles; t += nwaves){
    long r0 = (long)t*16;
    f32x4 acc[8] = {};
    const bf16_t* pa = Aagg + (r0 + r_lo)*FDIM + kgrp*8;
    const bf16_t* pi = Ain  + (r0 + r_lo)*FDIM + kgrp*8;
    #pragma unroll
    for(int kk=0;kk<8;kk++){
      const bf16_t* ap = (kk<4) ? (pa + kk*32) : (pi + (kk-4)*32);
      bf16x8 a = *(const bf16x8*)ap;
      #pragma unroll
      for(int cb=0;cb<8;cb++){
        bf16x8 b = *(const bf16x8*)(Bp + (((kk<<3)|cb)*64 + lane)*8);
        acc[cb] = __builtin_amdgcn_mfma_f32_16x16x32_bf16(a, b, acc[cb], 0, 0, 0);
      }
    }
    // epilogue: C/D layout col=lane&15, row=(lane>>4)*4+reg  [m89]
    #pragma unroll
    for(int cb=0;cb<8;cb++){
      int col = cb*16 + r_lo;
      #pragma unroll
      for(int r=0;r<4;r++){
        long row = r0 + kgrp*4 + r;
        float v = acc[cb][r] + breg[cb];
        if(relu) v = fmaxf(v, 0.f);
        if(resf) v += (float)Ain[row*FDIM + col];
        if(outF) outF[row*FDIM + col] = v;
        else     outB[row*FDIM + col] = f2bf(v);
      }
    }
  }
}

extern "C" void kernel_launch(void* const* d_in, const int* in_sizes, int n_in,
                              void* d_out, int out_size, void* d_ws, size_t ws_size,
                              hipStream_t stream){
  const float* x     = (const float*)d_in[0];
  const int*   ei    = (const int*)  d_in[1];
  const float* Wrel  = (const float*)d_in[2];
  const float* brel  = (const float*)d_in[3];
  const float* Wroot = (const float*)d_in[4];
  float* out = (float*)d_out;

  const int N = NNODES;
  const int E = in_sizes[1] / 2;
  const int* srcv = ei;
  const int* dstv = ei + E;

  char* w = (char*)d_ws;
  auto alloc = [&](size_t b)->char*{ char* p = w; w += (b + 255) & ~(size_t)255; return p; };
  unsigned short* xb  = (unsigned short*)alloc((size_t)N*FDIM*2);
  unsigned short* h_a = (unsigned short*)alloc((size_t)N*FDIM*2);
  unsigned short* h_b = (unsigned short*)alloc((size_t)N*FDIM*2);
  unsigned short* agg = (unsigned short*)alloc((size_t)N*FDIM*2);
  int*    deg       = (int*)   alloc((size_t)N*4);
  int*    cnt       = (int*)   alloc((size_t)N*4);
  int*    row_start = (int*)   alloc((size_t)(N+1)*4);
  int*    csr       = (int*)   alloc((size_t)E*4);
  bf16_t* Bp        = (bf16_t*)alloc((size_t)NLAYERS*4096*8*2);
  int*    sums      = (int*)   alloc(512);

  hipMemsetAsync(deg, 0, (size_t)N*4, stream);
  hipMemsetAsync(cnt, 0, (size_t)N*4, stream);

  int eb = (E + 255) / 256;
  int nchunks = (N + 1023) / 1024;
  deg_kernel <<<eb, 256, 0, stream>>>(dstv, deg, E);
  scan1_kernel<<<nchunks, 256, 0, stream>>>(deg, row_start, sums, N);
  scan2_kernel<<<1, 128, 0, stream>>>(sums, nchunks);
  scan3_kernel<<<(N + 1 + 255)/256, 256, 0, stream>>>(row_start, sums, N, E);
  fill_kernel<<<eb, 256, 0, stream>>>(srcv, dstv, row_start, cnt, csr, E);
  wprep_kernel<<<(NLAYERS*4096 + 255)/256, 256, 0, stream>>>(Wrel, Wroot, Bp);
  cvt_kernel  <<<(N*FDIM/8 + 255)/256, 256, 0, stream>>>(x, xb);

  const int ntiles  = N / 16;       // 6250, exact
  const int gblocks = 1563;         // ~1 tile per wave
  const int nwaves  = gblocks * 4;

  typedef unsigned short us;
  struct Lay { const us* in; us* o; int relu; int res; };
  Lay L[5] = {
    { xb,  h_a, 1, 0 },   // h1 = relu(gc0(x))
    { h_a, h_b, 1, 1 },   // h2 = relu(gc1(h1)) + h1
    { h_b, h_a, 1, 1 },   // h3
    { h_a, h_b, 1, 1 },   // h4
    { h_b, 0,   0, 1 },   // h5 = gc4(h4) + h4  -> d_out (fp32)
  };
  for(int l=0; l<NLAYERS; l++){
    gather_kernel<<<N/4, 256, 0, stream>>>(L[l].in, row_start, csr, agg, N);
    gemm_kernel  <<<gblocks, 256, 0, stream>>>((const bf16_t*)agg, (const bf16_t*)L[l].in,
                                               Bp + (size_t)l*4096*8,
                                               brel + l*FDIM,
                                               (bf16_t*)L[l].o, (l==4)? out : nullptr,
                                               L[l].relu, L[l].res,
                                               ntiles, nwaves);
  }
}